// Round 7
// baseline (213.743 us; speedup 1.0000x reference)
//
#include <hip/hip_runtime.h>
#include <math.h>

#define NB 4
#define NS 512
#define NV 32000
#define NROWS (NB * NS)
#define KL_ALPHA 0.3f

typedef float floatx4 __attribute__((ext_vector_type(4)));

// ws layout (floats): [0:NROWS) klrow | [NROWS:2N) surp | [2N:3N) gval |
// [3N:4N) grval | [4N:5N) logZx | [5N:6N) logZy | [6N] counter (as int)
#define WS_KL    0
#define WS_SURP  (NROWS)
#define WS_G     (2 * NROWS)
#define WS_GR    (3 * NROWS)
#define WS_LZX   (4 * NROWS)
#define WS_LZY   (5 * NROWS)
#define WS_CNT   (6 * NROWS)

__global__ __launch_bounds__(256) void krow_fused(
        const float* __restrict__ logits,
        const float* __restrict__ ref_logits,
        const int* __restrict__ input_ids,
        const int* __restrict__ attention_mask,
        const int* __restrict__ word_ids,
        const int* __restrict__ word_lengths,
        const float* __restrict__ lufreq,
        const float* __restrict__ labels,
        const float* __restrict__ W_head,
        const float* __restrict__ b_head,
        float* __restrict__ ws,
        float* __restrict__ out) {
    const int row = blockIdx.x;             // 0..NROWS-1
    const int b = row / NS, s = row - b * NS;
    const size_t base = (size_t)(b * (NS + 1) + s) * NV;
    const floatx4* __restrict__ x4 = (const floatx4*)(logits + base);
    const floatx4* __restrict__ y4 = (const floatx4*)(ref_logits + base);
    const int tid = threadIdx.x;

    // ---- per-row streaming pass: sums of exp(x), exp(y), exp(y)*(y-x) ----
    float sx[4] = {0.f, 0.f, 0.f, 0.f};
    float sy[4] = {0.f, 0.f, 0.f, 0.f};
    float ty[4] = {0.f, 0.f, 0.f, 0.f};

    for (int i = tid; i < NV / 4; i += 256) {
        floatx4 xv = x4[i];
        floatx4 yv = y4[i];
#pragma unroll
        for (int j = 0; j < 4; ++j) {
            float xe = xv[j], ye = yv[j];
            float ex = __expf(xe);
            float ey = __expf(ye);
            sx[j] += ex;
            sy[j] += ey;
            ty[j] = fmaf(ey, ye - xe, ty[j]);
        }
    }
    float Sx = (sx[0] + sx[1]) + (sx[2] + sx[3]);
    float Sy = (sy[0] + sy[1]) + (sy[2] + sy[3]);
    float Ty = (ty[0] + ty[1]) + (ty[2] + ty[3]);

    for (int off = 32; off > 0; off >>= 1) {
        Sx += __shfl_xor(Sx, off);
        Sy += __shfl_xor(Sy, off);
        Ty += __shfl_xor(Ty, off);
    }
    __shared__ float red[4][3];
    const int wave = tid >> 6, lane = tid & 63;
    if (lane == 0) { red[wave][0] = Sx; red[wave][1] = Sy; red[wave][2] = Ty; }
    __syncthreads();
    float tSx = 0.f, tSy = 0.f, tTy = 0.f;
#pragma unroll
    for (int w = 0; w < 4; ++w) { tSx += red[w][0]; tSy += red[w][1]; tTy += red[w][2]; }

    // guard: direct exp-sum valid unless overflow (inf/nan) or total underflow
    bool bad = !(tSx > 1e-35f) || !(tSy > 1e-35f) ||
               isinf(tSx) || isinf(tSy) || isinf(tTy) || isnan(tTy);

    float lzx, lzy, klv;
    if (!bad) {
        lzx = __logf(tSx);
        lzy = __logf(tSy);
        klv = tTy / tSy + lzx - lzy;
    } else {
        // rare fallback: max pass + shifted second pass (cache-warm)
        float mx = -INFINITY, my = -INFINITY;
        for (int i = tid; i < NV / 4; i += 256) {
            floatx4 xv = x4[i];
            floatx4 yv = y4[i];
            mx = fmaxf(mx, fmaxf(fmaxf(xv[0], xv[1]), fmaxf(xv[2], xv[3])));
            my = fmaxf(my, fmaxf(fmaxf(yv[0], yv[1]), fmaxf(yv[2], yv[3])));
        }
        for (int off = 32; off > 0; off >>= 1) {
            mx = fmaxf(mx, __shfl_xor(mx, off));
            my = fmaxf(my, __shfl_xor(my, off));
        }
        __syncthreads();
        if (lane == 0) { red[wave][0] = mx; red[wave][1] = my; }
        __syncthreads();
        float tMx = -INFINITY, tMy = -INFINITY;
#pragma unroll
        for (int w = 0; w < 4; ++w) {
            tMx = fmaxf(tMx, red[w][0]);
            tMy = fmaxf(tMy, red[w][1]);
        }
        float fsx = 0.f, fsy = 0.f, fty = 0.f;
        for (int i = tid; i < NV / 4; i += 256) {
            floatx4 xv = x4[i];
            floatx4 yv = y4[i];
#pragma unroll
            for (int j = 0; j < 4; ++j) {
                float xe = xv[j], ye = yv[j];
                fsx += __expf(xe - tMx);
                float ey = __expf(ye - tMy);
                fsy += ey;
                fty = fmaf(ey, ye - xe, fty);
            }
        }
        for (int off = 32; off > 0; off >>= 1) {
            fsx += __shfl_xor(fsx, off);
            fsy += __shfl_xor(fsy, off);
            fty += __shfl_xor(fty, off);
        }
        __syncthreads();
        if (lane == 0) { red[wave][0] = fsx; red[wave][1] = fsy; red[wave][2] = fty; }
        __syncthreads();
        float gSx = 0.f, gSy = 0.f, gTy = 0.f;
#pragma unroll
        for (int w = 0; w < 4; ++w) { gSx += red[w][0]; gSy += red[w][1]; gTy += red[w][2]; }
        lzx = tMx + __logf(gSx);
        lzy = tMy + __logf(gSy);
        klv = gTy / gSy + lzx - lzy;
    }

    if (tid == 0) {
        ws[WS_LZX + row] = lzx;
        ws[WS_LZY + row] = lzy;
        ws[WS_KL + row] = klv;
        int id0 = input_ids[b * NS + s];
        ws[WS_SURP + row] = lzx - logits[base + id0];
        if (s < NS - 1) {
            int id1 = input_ids[b * NS + s + 1];
            ws[WS_G + row]  = logits[base + id1] - lzx;
            ws[WS_GR + row] = ref_logits[base + id1] - lzy;
        } else {
            ws[WS_G + row] = 0.f;
            ws[WS_GR + row] = 0.f;
        }
    }

    // ---- last-block-finalizes ----
    __shared__ int is_last;
    if (tid == 0) {
        __threadfence();   // release this block's ws writes
        int old = atomicAdd((int*)(ws + WS_CNT), 1);
        is_last = (old == NROWS - 1) ? 1 : 0;
    }
    __syncthreads();
    if (!is_last) return;
    __threadfence();       // acquire all blocks' ws writes

    __shared__ float summed[NROWS];   // 8 KB
    for (int p = tid; p < NROWS; p += 256) summed[p] = 0.f;
    __syncthreads();
    for (int p = tid; p < NROWS; p += 256) {
        int bb = p / NS;
        int wid = word_ids[p];
        if (wid >= 0 && wid < NS) atomicAdd(&summed[bb * NS + wid], ws[WS_SURP + p]);
    }
    __syncthreads();

    const float W0 = W_head[0], W1 = W_head[1], W2 = W_head[2], bh = b_head[0];
    float mse_n = 0.f, mse_d = 0.f, kl_n = 0.f, kl_d = 0.f;
    float g_n = 0.f, gr_n = 0.f, g_d = 0.f;
    for (int p = tid; p < NROWS; p += 256) {
        int bb = p / NS, ss = p - bb * NS;
        int wid = word_ids[p];
        bool valid = (wid >= 0) && (wid < NS);
        int safe = wid < 0 ? 0 : (wid > NS - 1 ? NS - 1 : wid);
        int lens = word_lengths[bb * NS + safe];
        valid = valid && (lens != -1);
        float el = valid ? (float)lens : 0.f;
        float ef = valid ? lufreq[bb * NS + safe] : 0.f;
        float pred = summed[p] * W0 + el * W1 + ef * W2 + bh;
        out[1 + p] = pred;
        float lab = labels[p];
        float mw = (lab != -1.0f) ? 1.f : 0.f;
        float diff = lab - pred;
        mse_n += diff * diff * mw;
        mse_d += mw;
        float km = (ss == 0) ? 0.f : ((word_ids[p - 1] != -1) ? 1.f : 0.f);
        kl_n += ws[WS_KL + p] * km;
        kl_d += km;
        if (ss < NS - 1) {
            float am = (float)attention_mask[bb * NS + ss + 1];
            g_n += ws[WS_G + p] * am;
            gr_n += ws[WS_GR + p] * am;
            g_d += am;
        }
    }
    for (int off = 32; off > 0; off >>= 1) {
        mse_n += __shfl_xor(mse_n, off);
        mse_d += __shfl_xor(mse_d, off);
        kl_n  += __shfl_xor(kl_n, off);
        kl_d  += __shfl_xor(kl_d, off);
        g_n   += __shfl_xor(g_n, off);
        gr_n  += __shfl_xor(gr_n, off);
        g_d   += __shfl_xor(g_d, off);
    }
    __shared__ float r2[4][7];
    if (lane == 0) {
        r2[wave][0] = mse_n; r2[wave][1] = mse_d;
        r2[wave][2] = kl_n;  r2[wave][3] = kl_d;
        r2[wave][4] = g_n;   r2[wave][5] = gr_n; r2[wave][6] = g_d;
    }
    __syncthreads();
    if (tid == 0) {
        float a0 = 0, a1 = 0, a2 = 0, a3 = 0, a4 = 0, a5 = 0, a6 = 0;
        for (int w = 0; w < 4; ++w) {
            a0 += r2[w][0]; a1 += r2[w][1]; a2 += r2[w][2]; a3 += r2[w][3];
            a4 += r2[w][4]; a5 += r2[w][5]; a6 += r2[w][6];
        }
        float mse = a0 / a1;
        float kl = a2 / a3;
        out[0] = mse + KL_ALPHA * kl;     // MSE_WEIGHT = 1
        out[1 + NROWS] = mse;
        out[2 + NROWS] = kl;
        out[3 + NROWS] = a4 / a6;
        out[4 + NROWS] = a4 / a6 - a5 / a6;
    }
}

extern "C" void kernel_launch(void* const* d_in, const int* in_sizes, int n_in,
                              void* d_out, int out_size, void* d_ws, size_t ws_size,
                              hipStream_t stream) {
    const float* logits        = (const float*)d_in[0];
    const float* ref_logits    = (const float*)d_in[1];
    const int*   input_ids     = (const int*)d_in[2];
    const int*   attention_mask= (const int*)d_in[3];
    const int*   word_ids      = (const int*)d_in[4];
    const int*   word_lengths  = (const int*)d_in[5];
    const float* lufreq        = (const float*)d_in[6];
    const float* labels        = (const float*)d_in[7];
    const float* W_head        = (const float*)d_in[8];
    const float* b_head        = (const float*)d_in[9];
    float* out = (float*)d_out;
    float* ws = (float*)d_ws;

    // reset the finalize counter (deterministic every call; async = capturable)
    (void)hipMemsetAsync(ws + WS_CNT, 0, sizeof(int), stream);

    hipLaunchKernelGGL(krow_fused, dim3(NROWS), dim3(256), 0, stream,
                       logits, ref_logits, input_ids, attention_mask,
                       word_ids, word_lengths, lufreq, labels,
                       W_head, b_head, ws, out);
}

// Round 8
// 94.436 us; speedup vs baseline: 2.2634x; 2.2634x over previous
//
#include <hip/hip_runtime.h>
#include <math.h>

#define NB 4
#define NS 512
#define NV 32000
#define NROWS (NB * NS)
#define KL_ALPHA 0.3f

typedef float floatx4 __attribute__((ext_vector_type(4)));

// Kernel A: per-row (b,s) softmax stats for logits (x) and ref_logits (y).
// One block per row. Simple streaming loop (R2 structure, VGPR ~24-28) with
// nontemporal loads (R6-vs-R7 isolated +25% within equal code).
__global__ __launch_bounds__(256) void krow(const float* __restrict__ logits,
                                            const float* __restrict__ ref_logits,
                                            const int* __restrict__ input_ids,
                                            float* __restrict__ logZx,
                                            float* __restrict__ logZy,
                                            float* __restrict__ klrow,
                                            float* __restrict__ surp,
                                            float* __restrict__ gval,
                                            float* __restrict__ grval) {
    const int row = blockIdx.x;             // 0..NROWS-1
    const int b = row / NS, s = row - b * NS;
    const size_t base = (size_t)(b * (NS + 1) + s) * NV;
    const floatx4* __restrict__ x4 = (const floatx4*)(logits + base);
    const floatx4* __restrict__ y4 = (const floatx4*)(ref_logits + base);
    const int tid = threadIdx.x;

    // independent accumulator chains (pure adds — no serial exp recurrence)
    float sx[4] = {0.f, 0.f, 0.f, 0.f};
    float sy[4] = {0.f, 0.f, 0.f, 0.f};
    float ty[4] = {0.f, 0.f, 0.f, 0.f};

    for (int i = tid; i < NV / 4; i += 256) {
        floatx4 xv = __builtin_nontemporal_load(&x4[i]);
        floatx4 yv = __builtin_nontemporal_load(&y4[i]);
#pragma unroll
        for (int j = 0; j < 4; ++j) {
            float xe = xv[j], ye = yv[j];
            float ex = __expf(xe);
            float ey = __expf(ye);
            sx[j] += ex;
            sy[j] += ey;
            ty[j] = fmaf(ey, ye - xe, ty[j]);
        }
    }
    float Sx = (sx[0] + sx[1]) + (sx[2] + sx[3]);
    float Sy = (sy[0] + sy[1]) + (sy[2] + sy[3]);
    float Ty = (ty[0] + ty[1]) + (ty[2] + ty[3]);

    // wave butterfly reduce (64 lanes)
    for (int off = 32; off > 0; off >>= 1) {
        Sx += __shfl_xor(Sx, off);
        Sy += __shfl_xor(Sy, off);
        Ty += __shfl_xor(Ty, off);
    }
    __shared__ float red[4][3];
    const int wave = tid >> 6, lane = tid & 63;
    if (lane == 0) { red[wave][0] = Sx; red[wave][1] = Sy; red[wave][2] = Ty; }
    __syncthreads();
    float tSx = 0.f, tSy = 0.f, tTy = 0.f;
#pragma unroll
    for (int w = 0; w < 4; ++w) { tSx += red[w][0]; tSy += red[w][1]; tTy += red[w][2]; }

    // guard: direct exp-sum valid unless overflow (inf/nan) or total underflow
    bool bad = !(tSx > 1e-35f) || !(tSy > 1e-35f) ||
               isinf(tSx) || isinf(tSy) || isinf(tTy) || isnan(tTy);

    float lzx, lzy, klv;
    if (!bad) {
        lzx = __logf(tSx);
        lzy = __logf(tSy);
        klv = tTy / tSy + lzx - lzy;
    } else {
        // rare fallback: max pass + shifted second pass (cache-warm)
        float mx = -INFINITY, my = -INFINITY;
        for (int i = tid; i < NV / 4; i += 256) {
            floatx4 xv = x4[i];
            floatx4 yv = y4[i];
            mx = fmaxf(mx, fmaxf(fmaxf(xv[0], xv[1]), fmaxf(xv[2], xv[3])));
            my = fmaxf(my, fmaxf(fmaxf(yv[0], yv[1]), fmaxf(yv[2], yv[3])));
        }
        for (int off = 32; off > 0; off >>= 1) {
            mx = fmaxf(mx, __shfl_xor(mx, off));
            my = fmaxf(my, __shfl_xor(my, off));
        }
        __syncthreads();
        if (lane == 0) { red[wave][0] = mx; red[wave][1] = my; }
        __syncthreads();
        float tMx = -INFINITY, tMy = -INFINITY;
#pragma unroll
        for (int w = 0; w < 4; ++w) {
            tMx = fmaxf(tMx, red[w][0]);
            tMy = fmaxf(tMy, red[w][1]);
        }
        float fsx = 0.f, fsy = 0.f, fty = 0.f;
        for (int i = tid; i < NV / 4; i += 256) {
            floatx4 xv = x4[i];
            floatx4 yv = y4[i];
#pragma unroll
            for (int j = 0; j < 4; ++j) {
                float xe = xv[j], ye = yv[j];
                fsx += __expf(xe - tMx);
                float ey = __expf(ye - tMy);
                fsy += ey;
                fty = fmaf(ey, ye - xe, fty);
            }
        }
        for (int off = 32; off > 0; off >>= 1) {
            fsx += __shfl_xor(fsx, off);
            fsy += __shfl_xor(fsy, off);
            fty += __shfl_xor(fty, off);
        }
        __syncthreads();
        if (lane == 0) { red[wave][0] = fsx; red[wave][1] = fsy; red[wave][2] = fty; }
        __syncthreads();
        float gSx = 0.f, gSy = 0.f, gTy = 0.f;
#pragma unroll
        for (int w = 0; w < 4; ++w) { gSx += red[w][0]; gSy += red[w][1]; gTy += red[w][2]; }
        lzx = tMx + __logf(gSx);
        lzy = tMy + __logf(gSy);
        klv = gTy / gSy + lzx - lzy;
    }

    if (tid == 0) {
        logZx[row] = lzx;
        logZy[row] = lzy;
        klrow[row] = klv;
        int id0 = input_ids[b * NS + s];
        surp[row] = lzx - logits[base + id0];
        if (s < NS - 1) {
            int id1 = input_ids[b * NS + s + 1];
            gval[row]  = logits[base + id1] - lzx;
            grval[row] = ref_logits[base + id1] - lzy;
        } else {
            gval[row] = 0.f;
            grval[row] = 0.f;
        }
    }
}

// Kernel B: single block finalize — scatter-add summed_surprisal, preds, all scalars.
__global__ __launch_bounds__(1024) void kfinal(const int* __restrict__ input_ids,
                                               const int* __restrict__ attention_mask,
                                               const int* __restrict__ word_ids,
                                               const int* __restrict__ word_lengths,
                                               const float* __restrict__ lufreq,
                                               const float* __restrict__ labels,
                                               const float* __restrict__ W_head,
                                               const float* __restrict__ b_head,
                                               const float* __restrict__ logZx,
                                               const float* __restrict__ logZy,
                                               const float* __restrict__ klrow,
                                               const float* __restrict__ surp,
                                               const float* __restrict__ gval,
                                               const float* __restrict__ grval,
                                               float* __restrict__ out) {
    __shared__ float summed[NROWS];   // 8 KB: summed_surprisal (B,S)
    const int tid = threadIdx.x;
    for (int p = tid; p < NROWS; p += 1024) summed[p] = 0.f;
    __syncthreads();
    for (int p = tid; p < NROWS; p += 1024) {
        int b = p / NS;
        int wid = word_ids[p];
        if (wid >= 0 && wid < NS) atomicAdd(&summed[b * NS + wid], surp[p]);
    }
    __syncthreads();

    const float W0 = W_head[0], W1 = W_head[1], W2 = W_head[2], bh = b_head[0];
    float mse_n = 0.f, mse_d = 0.f, kl_n = 0.f, kl_d = 0.f;
    float g_n = 0.f, gr_n = 0.f, g_d = 0.f;
    for (int p = tid; p < NROWS; p += 1024) {
        int b = p / NS, s = p - b * NS;
        int wid = word_ids[p];
        bool valid = (wid >= 0) && (wid < NS);
        int safe = wid < 0 ? 0 : (wid > NS - 1 ? NS - 1 : wid);
        int lens = word_lengths[b * NS + safe];
        valid = valid && (lens != -1);
        float el = valid ? (float)lens : 0.f;
        float ef = valid ? lufreq[b * NS + safe] : 0.f;
        float pred = summed[p] * W0 + el * W1 + ef * W2 + bh;
        out[1 + p] = pred;
        float lab = labels[p];
        float mw = (lab != -1.0f) ? 1.f : 0.f;
        float diff = lab - pred;
        mse_n += diff * diff * mw;
        mse_d += mw;
        float km = (s == 0) ? 0.f : ((word_ids[p - 1] != -1) ? 1.f : 0.f);
        kl_n += klrow[p] * km;
        kl_d += km;
        if (s < NS - 1) {
            float am = (float)attention_mask[b * NS + s + 1];
            g_n += gval[p] * am;
            gr_n += grval[p] * am;
            g_d += am;
        }
    }
    for (int off = 32; off > 0; off >>= 1) {
        mse_n += __shfl_xor(mse_n, off);
        mse_d += __shfl_xor(mse_d, off);
        kl_n  += __shfl_xor(kl_n, off);
        kl_d  += __shfl_xor(kl_d, off);
        g_n   += __shfl_xor(g_n, off);
        gr_n  += __shfl_xor(gr_n, off);
        g_d   += __shfl_xor(g_d, off);
    }
    __shared__ float r2[16][7];
    const int wave = tid >> 6, lane = tid & 63;
    if (lane == 0) {
        r2[wave][0] = mse_n; r2[wave][1] = mse_d;
        r2[wave][2] = kl_n;  r2[wave][3] = kl_d;
        r2[wave][4] = g_n;   r2[wave][5] = gr_n; r2[wave][6] = g_d;
    }
    __syncthreads();
    if (tid == 0) {
        float a0 = 0, a1 = 0, a2 = 0, a3 = 0, a4 = 0, a5 = 0, a6 = 0;
        for (int w = 0; w < 16; ++w) {
            a0 += r2[w][0]; a1 += r2[w][1]; a2 += r2[w][2]; a3 += r2[w][3];
            a4 += r2[w][4]; a5 += r2[w][5]; a6 += r2[w][6];
        }
        float mse = a0 / a1;
        float kl = a2 / a3;
        float loss = mse + KL_ALPHA * kl;   // MSE_WEIGHT = 1
        float avg = a4 / a6;
        float delta = avg - a5 / a6;
        out[0] = loss;
        out[1 + NROWS] = mse;
        out[2 + NROWS] = kl;
        out[3 + NROWS] = avg;
        out[4 + NROWS] = delta;
    }
}

extern "C" void kernel_launch(void* const* d_in, const int* in_sizes, int n_in,
                              void* d_out, int out_size, void* d_ws, size_t ws_size,
                              hipStream_t stream) {
    const float* logits        = (const float*)d_in[0];
    const float* ref_logits    = (const float*)d_in[1];
    const int*   input_ids     = (const int*)d_in[2];
    const int*   attention_mask= (const int*)d_in[3];
    const int*   word_ids      = (const int*)d_in[4];
    const int*   word_lengths  = (const int*)d_in[5];
    const float* lufreq        = (const float*)d_in[6];
    const float* labels        = (const float*)d_in[7];
    const float* W_head        = (const float*)d_in[8];
    const float* b_head        = (const float*)d_in[9];
    float* out = (float*)d_out;
    float* ws = (float*)d_ws;

    float* logZx = ws;
    float* logZy = ws + NROWS;
    float* klrow = ws + 2 * NROWS;
    float* surp  = ws + 3 * NROWS;
    float* gvals = ws + 4 * NROWS;
    float* grvals= ws + 5 * NROWS;

    hipLaunchKernelGGL(krow, dim3(NROWS), dim3(256), 0, stream,
                       logits, ref_logits, input_ids,
                       logZx, logZy, klrow, surp, gvals, grvals);
    hipLaunchKernelGGL(kfinal, dim3(1), dim3(1024), 0, stream,
                       input_ids, attention_mask, word_ids, word_lengths,
                       lufreq, labels, W_head, b_head,
                       logZx, logZy, klrow, surp, gvals, grvals, out);
}

// Round 9
// 91.161 us; speedup vs baseline: 2.3447x; 1.0359x over previous
//
#include <hip/hip_runtime.h>
#include <math.h>

#define NB 4
#define NS 512
#define NV 32000
#define NROWS (NB * NS)
#define KL_ALPHA 0.3f
#define NIT 31   /* full 256-thread iterations per row; tail of 64 float4 */

typedef float floatx4 __attribute__((ext_vector_type(4)));

// per-element accumulation: sums of exp(x), exp(y), exp(y)*(y-x)
__device__ __forceinline__ void proc4(const floatx4& xv, const floatx4& yv,
                                      float* __restrict__ sx, float* __restrict__ sy,
                                      float* __restrict__ ty) {
#pragma unroll
    for (int j = 0; j < 4; ++j) {
        float xe = xv[j], ye = yv[j];
        float ex = __expf(xe);
        float ey = __expf(ye);
        sx[j] += ex;
        sy[j] += ey;
        ty[j] = fmaf(ey, ye - xe, ty[j]);
    }
}

// Kernel A: per-row (b,s) softmax stats for logits (x) and ref_logits (y).
// One block per row. Nontemporal loads (R8: +11%) + depth-4 pinned register
// pipeline (testing the pipeline×nt cell of the 2x2; R4 verified the
// construct materializes at VGPR~76).
__global__ __launch_bounds__(256) void krow(const float* __restrict__ logits,
                                            const float* __restrict__ ref_logits,
                                            const int* __restrict__ input_ids,
                                            float* __restrict__ logZx,
                                            float* __restrict__ logZy,
                                            float* __restrict__ klrow,
                                            float* __restrict__ surp,
                                            float* __restrict__ gval,
                                            float* __restrict__ grval) {
    const int row = blockIdx.x;             // 0..NROWS-1
    const int b = row / NS, s = row - b * NS;
    const size_t base = (size_t)(b * (NS + 1) + s) * NV;
    const floatx4* __restrict__ x4 = (const floatx4*)(logits + base);
    const floatx4* __restrict__ y4 = (const floatx4*)(ref_logits + base);
    const int tid = threadIdx.x;

    float sx[4] = {0.f, 0.f, 0.f, 0.f};
    float sy[4] = {0.f, 0.f, 0.f, 0.f};
    float ty[4] = {0.f, 0.f, 0.f, 0.f};

    // tail first (indices 7936..7999), single latency hit amortized over the row
    if (tid < 64) {
        floatx4 tx = __builtin_nontemporal_load(&x4[7936 + tid]);
        floatx4 tyv = __builtin_nontemporal_load(&y4[7936 + tid]);
        proc4(tx, tyv, sx, sy, ty);
    }

    // depth-4 pinned pipeline over the 31 full iterations
    floatx4 bx[4], by[4];
#pragma unroll
    for (int k = 0; k < 4; ++k) {
        bx[k] = __builtin_nontemporal_load(&x4[tid + k * 256]);
        by[k] = __builtin_nontemporal_load(&y4[tid + k * 256]);
    }
    __builtin_amdgcn_sched_barrier(0);
#pragma unroll
    for (int k = 0; k < NIT; ++k) {
        proc4(bx[k & 3], by[k & 3], sx, sy, ty);
        if (k + 4 < NIT) {
            bx[k & 3] = __builtin_nontemporal_load(&x4[tid + (k + 4) * 256]);
            by[k & 3] = __builtin_nontemporal_load(&y4[tid + (k + 4) * 256]);
        }
        __builtin_amdgcn_sched_barrier(0);   // loads for k+4 may not sink below here
    }

    float Sx = (sx[0] + sx[1]) + (sx[2] + sx[3]);
    float Sy = (sy[0] + sy[1]) + (sy[2] + sy[3]);
    float Ty = (ty[0] + ty[1]) + (ty[2] + ty[3]);

    // wave butterfly reduce (64 lanes)
    for (int off = 32; off > 0; off >>= 1) {
        Sx += __shfl_xor(Sx, off);
        Sy += __shfl_xor(Sy, off);
        Ty += __shfl_xor(Ty, off);
    }
    __shared__ float red[4][3];
    const int wave = tid >> 6, lane = tid & 63;
    if (lane == 0) { red[wave][0] = Sx; red[wave][1] = Sy; red[wave][2] = Ty; }
    __syncthreads();
    float tSx = 0.f, tSy = 0.f, tTy = 0.f;
#pragma unroll
    for (int w = 0; w < 4; ++w) { tSx += red[w][0]; tSy += red[w][1]; tTy += red[w][2]; }

    // guard: direct exp-sum valid unless overflow (inf/nan) or total underflow
    bool bad = !(tSx > 1e-35f) || !(tSy > 1e-35f) ||
               isinf(tSx) || isinf(tSy) || isinf(tTy) || isnan(tTy);

    float lzx, lzy, klv;
    if (!bad) {
        lzx = __logf(tSx);
        lzy = __logf(tSy);
        klv = tTy / tSy + lzx - lzy;
    } else {
        // rare fallback: max pass + shifted second pass (cache-warm)
        float mx = -INFINITY, my = -INFINITY;
        for (int i = tid; i < NV / 4; i += 256) {
            floatx4 xv = x4[i];
            floatx4 yv = y4[i];
            mx = fmaxf(mx, fmaxf(fmaxf(xv[0], xv[1]), fmaxf(xv[2], xv[3])));
            my = fmaxf(my, fmaxf(fmaxf(yv[0], yv[1]), fmaxf(yv[2], yv[3])));
        }
        for (int off = 32; off > 0; off >>= 1) {
            mx = fmaxf(mx, __shfl_xor(mx, off));
            my = fmaxf(my, __shfl_xor(my, off));
        }
        __syncthreads();
        if (lane == 0) { red[wave][0] = mx; red[wave][1] = my; }
        __syncthreads();
        float tMx = -INFINITY, tMy = -INFINITY;
#pragma unroll
        for (int w = 0; w < 4; ++w) {
            tMx = fmaxf(tMx, red[w][0]);
            tMy = fmaxf(tMy, red[w][1]);
        }
        float fsx = 0.f, fsy = 0.f, fty = 0.f;
        for (int i = tid; i < NV / 4; i += 256) {
            floatx4 xv = x4[i];
            floatx4 yv = y4[i];
#pragma unroll
            for (int j = 0; j < 4; ++j) {
                float xe = xv[j], ye = yv[j];
                fsx += __expf(xe - tMx);
                float ey = __expf(ye - tMy);
                fsy += ey;
                fty = fmaf(ey, ye - xe, fty);
            }
        }
        for (int off = 32; off > 0; off >>= 1) {
            fsx += __shfl_xor(fsx, off);
            fsy += __shfl_xor(fsy, off);
            fty += __shfl_xor(fty, off);
        }
        __syncthreads();
        if (lane == 0) { red[wave][0] = fsx; red[wave][1] = fsy; red[wave][2] = fty; }
        __syncthreads();
        float gSx = 0.f, gSy = 0.f, gTy = 0.f;
#pragma unroll
        for (int w = 0; w < 4; ++w) { gSx += red[w][0]; gSy += red[w][1]; gTy += red[w][2]; }
        lzx = tMx + __logf(gSx);
        lzy = tMy + __logf(gSy);
        klv = gTy / gSy + lzx - lzy;
    }

    if (tid == 0) {
        logZx[row] = lzx;
        logZy[row] = lzy;
        klrow[row] = klv;
        int id0 = input_ids[b * NS + s];
        surp[row] = lzx - logits[base + id0];
        if (s < NS - 1) {
            int id1 = input_ids[b * NS + s + 1];
            gval[row]  = logits[base + id1] - lzx;
            grval[row] = ref_logits[base + id1] - lzy;
        } else {
            gval[row] = 0.f;
            grval[row] = 0.f;
        }
    }
}

// Kernel B: single block finalize — scatter-add summed_surprisal, preds, all scalars.
__global__ __launch_bounds__(1024) void kfinal(const int* __restrict__ input_ids,
                                               const int* __restrict__ attention_mask,
                                               const int* __restrict__ word_ids,
                                               const int* __restrict__ word_lengths,
                                               const float* __restrict__ lufreq,
                                               const float* __restrict__ labels,
                                               const float* __restrict__ W_head,
                                               const float* __restrict__ b_head,
                                               const float* __restrict__ logZx,
                                               const float* __restrict__ logZy,
                                               const float* __restrict__ klrow,
                                               const float* __restrict__ surp,
                                               const float* __restrict__ gval,
                                               const float* __restrict__ grval,
                                               float* __restrict__ out) {
    __shared__ float summed[NROWS];   // 8 KB: summed_surprisal (B,S)
    const int tid = threadIdx.x;
    for (int p = tid; p < NROWS; p += 1024) summed[p] = 0.f;
    __syncthreads();
    for (int p = tid; p < NROWS; p += 1024) {
        int b = p / NS;
        int wid = word_ids[p];
        if (wid >= 0 && wid < NS) atomicAdd(&summed[b * NS + wid], surp[p]);
    }
    __syncthreads();

    const float W0 = W_head[0], W1 = W_head[1], W2 = W_head[2], bh = b_head[0];
    float mse_n = 0.f, mse_d = 0.f, kl_n = 0.f, kl_d = 0.f;
    float g_n = 0.f, gr_n = 0.f, g_d = 0.f;
    for (int p = tid; p < NROWS; p += 1024) {
        int b = p / NS, s = p - b * NS;
        int wid = word_ids[p];
        bool valid = (wid >= 0) && (wid < NS);
        int safe = wid < 0 ? 0 : (wid > NS - 1 ? NS - 1 : wid);
        int lens = word_lengths[b * NS + safe];
        valid = valid && (lens != -1);
        float el = valid ? (float)lens : 0.f;
        float ef = valid ? lufreq[b * NS + safe] : 0.f;
        float pred = summed[p] * W0 + el * W1 + ef * W2 + bh;
        out[1 + p] = pred;
        float lab = labels[p];
        float mw = (lab != -1.0f) ? 1.f : 0.f;
        float diff = lab - pred;
        mse_n += diff * diff * mw;
        mse_d += mw;
        float km = (s == 0) ? 0.f : ((word_ids[p - 1] != -1) ? 1.f : 0.f);
        kl_n += klrow[p] * km;
        kl_d += km;
        if (s < NS - 1) {
            float am = (float)attention_mask[b * NS + s + 1];
            g_n += gval[p] * am;
            gr_n += grval[p] * am;
            g_d += am;
        }
    }
    for (int off = 32; off > 0; off >>= 1) {
        mse_n += __shfl_xor(mse_n, off);
        mse_d += __shfl_xor(mse_d, off);
        kl_n  += __shfl_xor(kl_n, off);
        kl_d  += __shfl_xor(kl_d, off);
        g_n   += __shfl_xor(g_n, off);
        gr_n  += __shfl_xor(gr_n, off);
        g_d   += __shfl_xor(g_d, off);
    }
    __shared__ float r2[16][7];
    const int wave = tid >> 6, lane = tid & 63;
    if (lane == 0) {
        r2[wave][0] = mse_n; r2[wave][1] = mse_d;
        r2[wave][2] = kl_n;  r2[wave][3] = kl_d;
        r2[wave][4] = g_n;   r2[wave][5] = gr_n; r2[wave][6] = g_d;
    }
    __syncthreads();
    if (tid == 0) {
        float a0 = 0, a1 = 0, a2 = 0, a3 = 0, a4 = 0, a5 = 0, a6 = 0;
        for (int w = 0; w < 16; ++w) {
            a0 += r2[w][0]; a1 += r2[w][1]; a2 += r2[w][2]; a3 += r2[w][3];
            a4 += r2[w][4]; a5 += r2[w][5]; a6 += r2[w][6];
        }
        float mse = a0 / a1;
        float kl = a2 / a3;
        float loss = mse + KL_ALPHA * kl;   // MSE_WEIGHT = 1
        float avg = a4 / a6;
        float delta = avg - a5 / a6;
        out[0] = loss;
        out[1 + NROWS] = mse;
        out[2 + NROWS] = kl;
        out[3 + NROWS] = avg;
        out[4 + NROWS] = delta;
    }
}

extern "C" void kernel_launch(void* const* d_in, const int* in_sizes, int n_in,
                              void* d_out, int out_size, void* d_ws, size_t ws_size,
                              hipStream_t stream) {
    const float* logits        = (const float*)d_in[0];
    const float* ref_logits    = (const float*)d_in[1];
    const int*   input_ids     = (const int*)d_in[2];
    const int*   attention_mask= (const int*)d_in[3];
    const int*   word_ids      = (const int*)d_in[4];
    const int*   word_lengths  = (const int*)d_in[5];
    const float* lufreq        = (const float*)d_in[6];
    const float* labels        = (const float*)d_in[7];
    const float* W_head        = (const float*)d_in[8];
    const float* b_head        = (const float*)d_in[9];
    float* out = (float*)d_out;
    float* ws = (float*)d_ws;

    float* logZx = ws;
    float* logZy = ws + NROWS;
    float* klrow = ws + 2 * NROWS;
    float* surp  = ws + 3 * NROWS;
    float* gvals = ws + 4 * NROWS;
    float* grvals= ws + 5 * NROWS;

    hipLaunchKernelGGL(krow, dim3(NROWS), dim3(256), 0, stream,
                       logits, ref_logits, input_ids,
                       logZx, logZy, klrow, surp, gvals, grvals);
    hipLaunchKernelGGL(kfinal, dim3(1), dim3(1024), 0, stream,
                       input_ids, attention_mask, word_ids, word_lengths,
                       lufreq, labels, W_head, b_head,
                       logZx, logZy, klrow, surp, gvals, grvals, out);
}